// Round 1
// 356.750 us; speedup vs baseline: 1.0331x; 1.0331x over previous
//
#include <hip/hip_runtime.h>
#include <hip/hip_bf16.h>

// Decoder (EGNN) on MI355X. pos==0 identity => stage-2/pos/counts dead.
// Pipeline: memset(cntI), k_count, k_scan (CSR + wave-chunk items),
// k_bucket (+wfrag blocks 0-3, +g GEMM blocks 4-7),
// k_preA (An=nodef@eW1 GEMM + Ag=g@eW1; layer-0 A1/A2 separable since
// h=nodef[n]+g[bb]), k_pre1 (materialize h, A1t, A2bf -- pure memory),
// 4x{ k_edge (wave=24-edge chunk, MFMA, reg-only), k_post }.
// k_post v2: 256 blocks x 64 rows, 4x4 register tiles, activations stored
// TRANSPOSED in LDS (XT[k][row], stride 68). Per k-step: 1 b128 W + 1 b128 X
// per 16 FMA (prev: 32B W + 8B act per 8 FMA -> LDS-pipe-bound ~40us/inst).

namespace {

constexpr int kB = 16, kN = 1024, kH = 64, kE = 32768, kLat = 128;
constexpr int kC = 24;                 // edges per wave-chunk
constexpr int kMaxItems = 2560;        // >= sum ceil(deg/kC) (~2390)

typedef __attribute__((ext_vector_type(8))) short short8;   // 8 bf16
typedef __attribute__((ext_vector_type(4))) float floatx4;

__device__ __forceinline__ unsigned short f2bf(float f){   // RNE
  union { float f; unsigned int u; } v; v.f = f;
  unsigned int r = v.u + 0x7fffu + ((v.u >> 16) & 1u);
  return (unsigned short)(r >> 16);
}
__device__ __forceinline__ unsigned int packbf(float a, float b){
  return ((unsigned int)f2bf(b) << 16) | (unsigned int)f2bf(a);
}
__device__ __forceinline__ unsigned int pack2f(float a, float b){ // fast half-up
  unsigned int ua = __float_as_uint(a) + 0x8000u;
  unsigned int ub = __float_as_uint(b) + 0x8000u;
  return __builtin_amdgcn_perm(ub, ua, 0x07060302);
}
__device__ __forceinline__ float bflo(unsigned int u){
  union { unsigned int u; float f; } v; v.u = u << 16; return v.f;
}
__device__ __forceinline__ float bfhi(unsigned int u){
  union { unsigned int u; float f; } v; v.u = u & 0xffff0000u; return v.f;
}
__device__ __forceinline__ float silu2(float x){   // 2 trans + 3 alu
  float u = __builtin_amdgcn_exp2f(-1.44269504f * x);
  return x * __builtin_amdgcn_rcpf(1.0f + u);
}

// ---- CSR build -------------------------------------------------------------
__global__ void k_count(const int* ei, int* cntI){
  int e = blockIdx.x*256 + threadIdx.x;
  atomicAdd(&cntI[ei[e]], 1);
}

__global__ void k_scan(const int* cntI, int* off, int* ioff, int* fill,
                       int* items, int* nitems){
  __shared__ int s0[1024];
  __shared__ int s1[1024];
  int t = threadIdx.x;
  int c = cntI[t];
  s0[t] = c; __syncthreads();
  int* src = s0; int* dst = s1;
  for (int o = 1; o < 1024; o <<= 1){
    int v = src[t] + ((t >= o) ? src[t-o] : 0);
    dst[t] = v; __syncthreads();
    int* tmp = src; src = dst; dst = tmp;
  }
  int inc = src[t];
  off[t] = inc - c;
  if (t == 1023) off[1024] = inc;
  fill[t] = 0;
  int ic = (c + (kC-1)) / kC;
  __syncthreads();
  s0[t] = ic; __syncthreads();
  src = s0; dst = s1;
  for (int o = 1; o < 1024; o <<= 1){
    int v = src[t] + ((t >= o) ? src[t-o] : 0);
    dst[t] = v; __syncthreads();
    int* tmp = src; src = dst; dst = tmp;
  }
  int inc2 = src[t];
  int ib = inc2 - ic;
  ioff[t] = ib;
  if (t == 1023){ ioff[1024] = inc2; *nitems = inc2; }
  for (int s = 0; s < ic; s++) items[ib + s] = (t << 12) | s;
}

// ---- bucket + wfrag (blocks 0-3) + g GEMM (blocks 4-7) ---------------------
__global__ void k_bucket(const int* ei, const int* off, int* fill, int* ecol,
                         const float* eW2, unsigned short* wfragE,
                         const float* z, const float* Wg, const float* bg,
                         float* g){
  int e = blockIdx.x*256 + threadIdx.x;
  int r = ei[e];
  int s = atomicAdd(&fill[r], 1);
  ecol[off[r] + s] = ei[kE + e];
  if (blockIdx.x < 4){
    int l = blockIdx.x;
    for (int i = threadIdx.x; i < 4096; i += 256){
      int f = i >> 9, lane = (i >> 3) & 63, j8 = i & 7;
      int jt = f >> 1, ks = f & 1;
      int k = ks*32 + (lane >> 4)*8 + j8;
      int j = jt*16 + (lane & 15);
      wfragE[l*4096 + i] = f2bf(eW2[l*4096 + k*64 + j]);
    }
  } else if (blockIdx.x < 8){
    int b = (blockIdx.x - 4)*4 + (threadIdx.x >> 6);
    int j = threadIdx.x & 63;
    float acc = bg[j];
    for (int k = 0; k < kLat; k++) acc += z[b*kLat + k] * Wg[k*64 + j];
    g[b*64 + j] = acc;
  }
}

// ---- shared GEMM helpers for the 4x4-tile kernels --------------------------
__device__ __forceinline__ void stage16k(float* Wl, const float* src, int tid){
  const float4* p = (const float4*)src;
  float4* d = (float4*)Wl;
  d[tid]       = p[tid];
  d[tid + 256] = p[tid + 256];
  d[tid + 512] = p[tid + 512];
  d[tid + 768] = p[tid + 768];
}
__device__ __forceinline__ void xtwrite(float* XTl, int j0, int r0,
                                        const float v[4][4]){
  #pragma unroll
  for (int j = 0; j < 4; j++){
    float4 t = { v[0][j], v[1][j], v[2][j], v[3][j] };
    *(float4*)(XTl + (j0 + j)*68 + r0) = t;
  }
}
__device__ __forceinline__ void gemm64(const float* Wl, const float* XTl,
                                       int j0, int r0, float acc[4][4]){
  #pragma unroll 4
  for (int k = 0; k < 64; k++){
    float4 w = *(const float4*)(Wl + k*64 + j0);
    float4 x = *(const float4*)(XTl + k*68 + r0);
    float xv[4] = { x.x, x.y, x.z, x.w };
    float wv[4] = { w.x, w.y, w.z, w.w };
    #pragma unroll
    for (int i = 0; i < 4; i++)
      #pragma unroll
      for (int j = 0; j < 4; j++)
        acc[i][j] += xv[i]*wv[j];
  }
}

// ---- k_preA: An1/An2 = (nf@Wn+bn)@eW1 (blocks 0-63, 16 nodes each);
// ----         Ag1/Ag2 = g@eW1 (block 64). Layer-0 separability. ------------
__global__ __launch_bounds__(256, 1) void k_preA(const float* nf, const float* Wn,
      const float* bn, const float* g, const float* eW1, const float* eb1,
      float* An1, float* An2, float* Ag1, float* Ag2){
  __shared__ __align__(16) float W0[4096];
  __shared__ __align__(16) float W1[4096];
  __shared__ __align__(16) float HR[16*68];
  int tid = threadIdx.x;
  if (blockIdx.x == 64){
    int bb = tid >> 4, j0 = (tid & 15)*4;
    float a1[4] = {0.f,0.f,0.f,0.f}, a2[4] = {0.f,0.f,0.f,0.f};
    for (int k = 0; k < 64; k++){
      float gk = g[bb*64 + k];
      float4 w1 = *(const float4*)(eW1 + k*64 + j0);
      float4 w2 = *(const float4*)(eW1 + 4096 + k*64 + j0);
      a1[0] += gk*w1.x; a1[1] += gk*w1.y; a1[2] += gk*w1.z; a1[3] += gk*w1.w;
      a2[0] += gk*w2.x; a2[1] += gk*w2.y; a2[2] += gk*w2.z; a2[3] += gk*w2.w;
    }
    float4 o1 = { a1[0], a1[1], a1[2], a1[3] };
    float4 o2 = { a2[0], a2[1], a2[2], a2[3] };
    *(float4*)(Ag1 + bb*64 + j0) = o1;
    *(float4*)(Ag2 + bb*64 + j0) = o2;
    return;
  }
  {
    const float4* e1a = (const float4*)(eW1);
    const float4* e1b = (const float4*)(eW1 + 4096);
    for (int i = tid; i < 1024; i += 256){
      ((float4*)W0)[i] = e1a[i]; ((float4*)W1)[i] = e1b[i];
    }
  }
  int rl = tid >> 4, c = tid & 15, j0 = c*4;
  int n = blockIdx.x*16 + rl;
  float f0 = nf[n*3], f1 = nf[n*3+1], f2 = nf[n*3+2];
  float4 hv;
  hv.x = f0*Wn[j0+0] + f1*Wn[64+j0+0] + f2*Wn[128+j0+0] + bn[j0+0];
  hv.y = f0*Wn[j0+1] + f1*Wn[64+j0+1] + f2*Wn[128+j0+1] + bn[j0+1];
  hv.z = f0*Wn[j0+2] + f1*Wn[64+j0+2] + f2*Wn[128+j0+2] + bn[j0+2];
  hv.w = f0*Wn[j0+3] + f1*Wn[64+j0+3] + f2*Wn[128+j0+3] + bn[j0+3];
  *(float4*)(HR + rl*68 + j0) = hv;
  __syncthreads();
  float4 b1 = *(const float4*)(eb1 + j0);
  float a1[4] = { b1.x, b1.y, b1.z, b1.w };
  float a2[4] = { 0.f, 0.f, 0.f, 0.f };
  #pragma unroll 8
  for (int k = 0; k < 64; k++){
    float hk = HR[rl*68 + k];
    float4 w1 = *(const float4*)(W0 + k*64 + j0);
    float4 w2 = *(const float4*)(W1 + k*64 + j0);
    a1[0] += hk*w1.x; a1[1] += hk*w1.y; a1[2] += hk*w1.z; a1[3] += hk*w1.w;
    a2[0] += hk*w2.x; a2[1] += hk*w2.y; a2[2] += hk*w2.z; a2[3] += hk*w2.w;
  }
  float4 o1 = { a1[0], a1[1], a1[2], a1[3] };
  float4 o2 = { a2[0], a2[1], a2[2], a2[3] };
  *(float4*)(An1 + n*64 + j0) = o1;
  *(float4*)(An2 + n*64 + j0) = o2;
}

// ---- k_pre1: materialize h = nodef+g, A1t = An1+Ag1, A2bf = bf16(An2+Ag2) --
__global__ __launch_bounds__(256, 1) void k_pre1(const float* nf, const float* Wn,
      const float* bn, const float* g, const float* An1, const float* An2,
      const float* Ag1, const float* Ag2, float* h, float* A1t,
      unsigned short* A2bf){
  int idx = blockIdx.x*256 + threadIdx.x;
  int row = idx >> 4;          // n*16 + bb
  int j0  = (idx & 15) * 4;
  int n = row >> 4, bb = row & 15;
  float4 a1 = *(const float4*)(An1 + n*64 + j0);
  float4 g1 = *(const float4*)(Ag1 + bb*64 + j0);
  a1.x += g1.x; a1.y += g1.y; a1.z += g1.z; a1.w += g1.w;
  *(float4*)(A1t + row*64 + j0) = a1;
  float4 a2 = *(const float4*)(An2 + n*64 + j0);
  float4 g2 = *(const float4*)(Ag2 + bb*64 + j0);
  a2.x += g2.x; a2.y += g2.y; a2.z += g2.z; a2.w += g2.w;
  uint2 pk; pk.x = packbf(a2.x, a2.y); pk.y = packbf(a2.z, a2.w);
  *(uint2*)(A2bf + row*64 + j0) = pk;
  float f0 = nf[n*3], f1 = nf[n*3+1], f2 = nf[n*3+2];
  float4 w0 = *(const float4*)(Wn + j0);
  float4 w1 = *(const float4*)(Wn + 64 + j0);
  float4 w2 = *(const float4*)(Wn + 128 + j0);
  float4 bv = *(const float4*)(bn + j0);
  float4 gv = *(const float4*)(g + bb*64 + j0);
  float4 hv;
  hv.x = f0*w0.x + f1*w1.x + f2*w2.x + bv.x + gv.x;
  hv.y = f0*w0.y + f1*w1.y + f2*w2.y + bv.y + gv.y;
  hv.z = f0*w0.z + f1*w1.z + f2*w2.z + bv.z + gv.z;
  hv.w = f0*w0.w + f1*w1.w + f2*w2.w + bv.w + gv.w;
  *(float4*)(h + (bb*1024 + n)*64 + j0) = hv;
}

// ---- hot kernel: wave = one (node, <=24-edge chunk); registers only --------
__global__ __launch_bounds__(256, 3) void k_edge(const float* A1t,
      const unsigned short* A2bf, const unsigned short* wfragE,
      const float* eb2, int l, const int* off, const int* ecol,
      const int* items, const int* nitems, float* P){
  int w = blockIdx.x*4 + (threadIdx.x >> 6);
  if (w >= *nitems) return;
  int lane = threadIdx.x & 63;
  int m = lane & 15, quad = lane >> 4;
  int it = items[w];
  int r = it >> 12, s = it & 4095;
  int e0 = off[r] + s*kC;
  int e1 = min(off[r+1], e0 + kC);

  short8 wf[8];
  #pragma unroll
  for (int f = 0; f < 8; f++)
    wf[f] = *(const short8*)(wfragE + l*4096 + f*512 + lane*8);

  float4 a1[4];
  #pragma unroll
  for (int ks = 0; ks < 2; ks++){
    a1[ks*2+0] = *(const float4*)(A1t + (r<<10) + (m<<6) + ks*32 + quad*8);
    a1[ks*2+1] = *(const float4*)(A1t + (r<<10) + (m<<6) + ks*32 + quad*8 + 4);
  }
  floatx4 dini[4];
  #pragma unroll
  for (int jt = 0; jt < 4; jt++)
    dini[jt] = *(const floatx4*)(eb2 + l*64 + jt*16 + quad*4);
  floatx4 agg[4];
  #pragma unroll
  for (int jt = 0; jt < 4; jt++) agg[jt] = (floatx4){0.f,0.f,0.f,0.f};

  int c0 = ecol[e0];
  uint4 p0 = *(const uint4*)(A2bf + ((c0<<4)+m)*64 + quad*8);
  uint4 p1 = *(const uint4*)(A2bf + ((c0<<4)+m)*64 + 32 + quad*8);

  for (int e = e0; e < e1; e++){
    uint4 c_0 = p0, c_1 = p1;
    if (e + 1 < e1){
      int cn = ecol[e+1];
      p0 = *(const uint4*)(A2bf + ((cn<<4)+m)*64 + quad*8);
      p1 = *(const uint4*)(A2bf + ((cn<<4)+m)*64 + 32 + quad*8);
    }
    short8 bfr[2];
    #pragma unroll
    for (int ks = 0; ks < 2; ks++){
      uint4 a2r = (ks == 0) ? c_0 : c_1;
      float4 x0 = a1[ks*2+0];
      float4 x1 = a1[ks*2+1];
      float v0 = silu2(x0.x + bflo(a2r.x));
      float v1 = silu2(x0.y + bfhi(a2r.x));
      float v2 = silu2(x0.z + bflo(a2r.y));
      float v3 = silu2(x0.w + bfhi(a2r.y));
      float v4 = silu2(x1.x + bflo(a2r.z));
      float v5 = silu2(x1.y + bfhi(a2r.z));
      float v6 = silu2(x1.z + bflo(a2r.w));
      float v7 = silu2(x1.w + bfhi(a2r.w));
      union { uint4 u; short8 s; } bu;
      bu.u.x = pack2f(v0, v1); bu.u.y = pack2f(v2, v3);
      bu.u.z = pack2f(v4, v5); bu.u.w = pack2f(v6, v7);
      bfr[ks] = bu.s;
    }
    #pragma unroll
    for (int jt = 0; jt < 4; jt++){
      floatx4 d = dini[jt];
      d = __builtin_amdgcn_mfma_f32_16x16x32_bf16(wf[jt*2+0], bfr[0], d, 0, 0, 0);
      d = __builtin_amdgcn_mfma_f32_16x16x32_bf16(wf[jt*2+1], bfr[1], d, 0, 0, 0);
      floatx4 a = agg[jt];
      a.x += silu2(d.x); a.y += silu2(d.y);
      a.z += silu2(d.z); a.w += silu2(d.w);
      agg[jt] = a;
    }
  }
  #pragma unroll
  for (int jt = 0; jt < 4; jt++)
    *(floatx4*)(P + w*1024 + m*64 + jt*16 + quad*4) = agg[jt];
}

// ---- k_post v2: 256 blocks x 64 rows (one bb, 64 nodes), 4x4 reg tiles -----
// LDS: W (16KB, current weight half) + XT (17KB, transposed activations).
// Phases: [W=nW1lo, XT=h^T] G1a | [W=nW1hi, XT=ag^T] G1b,silu |
// [W=nW2, XT=t^T] G2,resid,LN | [W=eW1lo(l+1), XT=hn^T] a1 | [W=eW1hi] a2
// (LAST: [W=oW1, XT=hn^T] relu-head + in-reg oW2 reduce).
template <bool LAST>
__global__ __launch_bounds__(256, 1) void k_post(int l, float* h, const float* P,
      const int* ioff, const float* nW1, const float* nb1_, const float* nW2,
      const float* nb2_, const float* lng_, const float* lnb_,
      const float* eW1, const float* eb1_, float* A1t, unsigned short* A2bf,
      const float* oW1, const float* ob1_, const float* oW2, const float* ob2_,
      float* out){
  __shared__ __align__(16) float W[4096];
  __shared__ __align__(16) float XT[64*68];
  int tid = threadIdx.x;
  int bb = blockIdx.x >> 4;
  int n0 = (blockIdx.x & 15) * 64;
  int c = tid & 15, g = tid >> 4;
  int j0 = c*4, r0 = g*4;
  int rowbase = bb*1024 + n0 + r0;

  stage16k(W, nW1 + l*8192, tid);
  float hold[4][4];
  #pragma unroll
  for (int i = 0; i < 4; i++){
    float4 v = *(const float4*)(h + (rowbase + i)*64 + j0);
    hold[i][0]=v.x; hold[i][1]=v.y; hold[i][2]=v.z; hold[i][3]=v.w;
  }
  xtwrite(XT, j0, r0, hold);
  float acc[4][4];
  {
    float4 b1 = *(const float4*)(nb1_ + l*64 + j0);
    float bv[4] = { b1.x, b1.y, b1.z, b1.w };
    #pragma unroll
    for (int i = 0; i < 4; i++)
      #pragma unroll
      for (int j = 0; j < 4; j++) acc[i][j] = bv[j];
  }
  __syncthreads();
  gemm64(W, XT, j0, r0, acc);            // t += h @ nW1lo
  __syncthreads();

  stage16k(W, nW1 + l*8192 + 4096, tid);
  {
    float agt[4][4];
    #pragma unroll
    for (int i = 0; i < 4; i++){
      int n = n0 + r0 + i;
      float4 s = { 0.f, 0.f, 0.f, 0.f };
      int i0 = ioff[n], i1 = ioff[n+1];
      for (int it = i0; it < i1; it++){
        float4 v = *(const float4*)(P + it*1024 + bb*64 + j0);
        s.x += v.x; s.y += v.y; s.z += v.z; s.w += v.w;
      }
      agt[i][0]=s.x; agt[i][1]=s.y; agt[i][2]=s.z; agt[i][3]=s.w;
    }
    xtwrite(XT, j0, r0, agt);
  }
  __syncthreads();
  gemm64(W, XT, j0, r0, acc);            // t += agg @ nW1hi
  #pragma unroll
  for (int i = 0; i < 4; i++)
    #pragma unroll
    for (int j = 0; j < 4; j++) acc[i][j] = silu2(acc[i][j]);
  __syncthreads();

  stage16k(W, nW2 + l*4096, tid);
  xtwrite(XT, j0, r0, acc);
  float u[4][4];
  {
    float4 b2 = *(const float4*)(nb2_ + l*64 + j0);
    float bv[4] = { b2.x, b2.y, b2.z, b2.w };
    #pragma unroll
    for (int i = 0; i < 4; i++)
      #pragma unroll
      for (int j = 0; j < 4; j++) u[i][j] = bv[j];
  }
  __syncthreads();
  gemm64(W, XT, j0, r0, u);              // u = t @ nW2 + nb2
  // residual + LayerNorm (rows reduce across the 16 c-lanes)
  float4 lgv = *(const float4*)(lng_ + l*64 + j0);
  float4 lbv = *(const float4*)(lnb_ + l*64 + j0);
  float hn[4][4];
  #pragma unroll
  for (int i = 0; i < 4; i++){
    float hv[4];
    #pragma unroll
    for (int j = 0; j < 4; j++) hv[j] = hold[i][j] + u[i][j];
    float s1 = hv[0]+hv[1]+hv[2]+hv[3];
    float s2 = hv[0]*hv[0]+hv[1]*hv[1]+hv[2]*hv[2]+hv[3]*hv[3];
    s1 += __shfl_xor(s1, 1, 64); s1 += __shfl_xor(s1, 2, 64);
    s1 += __shfl_xor(s1, 4, 64); s1 += __shfl_xor(s1, 8, 64);
    s2 += __shfl_xor(s2, 1, 64); s2 += __shfl_xor(s2, 2, 64);
    s2 += __shfl_xor(s2, 4, 64); s2 += __shfl_xor(s2, 8, 64);
    float mu  = s1 * (1.0f/64.0f);
    float var = s2 * (1.0f/64.0f) - mu*mu;
    float rs  = rsqrtf(var + 1e-5f);
    hn[i][0] = (hv[0]-mu)*rs*lgv.x + lbv.x;
    hn[i][1] = (hv[1]-mu)*rs*lgv.y + lbv.y;
    hn[i][2] = (hv[2]-mu)*rs*lgv.z + lbv.z;
    hn[i][3] = (hv[3]-mu)*rs*lgv.w + lbv.w;
  }

  if (!LAST){
    #pragma unroll
    for (int i = 0; i < 4; i++){
      float4 v = { hn[i][0], hn[i][1], hn[i][2], hn[i][3] };
      *(float4*)(h + (rowbase + i)*64 + j0) = v;
    }
    __syncthreads();
    stage16k(W, eW1 + (l+1)*8256, tid);
    xtwrite(XT, j0, r0, hn);
    float a1[4][4];
    {
      float4 b1 = *(const float4*)(eb1_ + (l+1)*64 + j0);
      float bv[4] = { b1.x, b1.y, b1.z, b1.w };
      #pragma unroll
      for (int i = 0; i < 4; i++)
        #pragma unroll
        for (int j = 0; j < 4; j++) a1[i][j] = bv[j];
    }
    __syncthreads();
    gemm64(W, XT, j0, r0, a1);           // A1 = hn @ eW1lo + eb1
    __syncthreads();
    stage16k(W, eW1 + (l+1)*8256 + 4096, tid);
    float a2[4][4];
    #pragma unroll
    for (int i = 0; i < 4; i++)
      #pragma unroll
      for (int j = 0; j < 4; j++) a2[i][j] = 0.f;
    __syncthreads();
    gemm64(W, XT, j0, r0, a2);           // A2 = hn @ eW1hi
    #pragma unroll
    for (int i = 0; i < 4; i++){
      int tb = ((n0 + r0 + i)*16 + bb)*64 + j0;
      float4 o1 = { a1[i][0], a1[i][1], a1[i][2], a1[i][3] };
      *(float4*)(A1t + tb) = o1;
      uint2 pk; pk.x = packbf(a2[i][0], a2[i][1]);
      pk.y = packbf(a2[i][2], a2[i][3]);
      *(uint2*)(A2bf + tb) = pk;
    }
  } else {
    __syncthreads();
    stage16k(W, oW1, tid);
    xtwrite(XT, j0, r0, hn);
    float tr[4][4];
    {
      float4 b1 = *(const float4*)(ob1_ + j0);
      float bv[4] = { b1.x, b1.y, b1.z, b1.w };
      #pragma unroll
      for (int i = 0; i < 4; i++)
        #pragma unroll
        for (int j = 0; j < 4; j++) tr[i][j] = bv[j];
    }
    __syncthreads();
    gemm64(W, XT, j0, r0, tr);           // t = hn @ oW1 + ob1
    #pragma unroll
    for (int i = 0; i < 4; i++)
      #pragma unroll
      for (int j = 0; j < 4; j++) tr[i][j] = fmaxf(tr[i][j], 0.f);
    // out = relu(t) @ oW2 + ob2, partial per thread then reduce over c-lanes
    float po[4][3];
    #pragma unroll
    for (int i = 0; i < 4; i++){ po[i][0]=0.f; po[i][1]=0.f; po[i][2]=0.f; }
    #pragma unroll
    for (int j = 0; j < 4; j++){
      float w0 = oW2[(j0+j)*3 + 0];
      float w1 = oW2[(j0+j)*3 + 1];
      float w2 = oW2[(j0+j)*3 + 2];
      #pragma unroll
      for (int i = 0; i < 4; i++){
        po[i][0] += tr[i][j]*w0;
        po[i][1] += tr[i][j]*w1;
        po[i][2] += tr[i][j]*w2;
      }
    }
    #pragma unroll
    for (int i = 0; i < 4; i++)
      #pragma unroll
      for (int uu = 0; uu < 3; uu++){
        float v = po[i][uu];
        v += __shfl_xor(v, 1, 64); v += __shfl_xor(v, 2, 64);
        v += __shfl_xor(v, 4, 64); v += __shfl_xor(v, 8, 64);
        po[i][uu] = v;
      }
    if (c == 0){
      #pragma unroll
      for (int i = 0; i < 4; i++){
        int n = n0 + r0 + i;
        out[bb*3072 + n*3 + 0] = po[i][0] + ob2_[0];
        out[bb*3072 + n*3 + 1] = po[i][1] + ob2_[1];
        out[bb*3072 + n*3 + 2] = po[i][2] + ob2_[2];
      }
    }
  }
}

} // namespace

extern "C" void kernel_launch(void* const* d_in, const int* in_sizes, int n_in,
                              void* d_out, int out_size, void* d_ws, size_t ws_size,
                              hipStream_t stream){
  const float* z   = (const float*)d_in[0];
  const int*   ei  = (const int*)d_in[1];
  const float* nf  = (const float*)d_in[2];
  const float* Wg  = (const float*)d_in[3];  const float* bg  = (const float*)d_in[4];
  const float* Wn  = (const float*)d_in[5];  const float* bn  = (const float*)d_in[6];
  const float* eW1 = (const float*)d_in[7];  const float* eb1 = (const float*)d_in[8];
  const float* eW2 = (const float*)d_in[9];  const float* eb2 = (const float*)d_in[10];
  const float* nW1 = (const float*)d_in[14]; const float* nb1 = (const float*)d_in[15];
  const float* nW2 = (const float*)d_in[16]; const float* nb2 = (const float*)d_in[17];
  const float* lng = (const float*)d_in[18]; const float* lnb = (const float*)d_in[19];
  const float* oW1 = (const float*)d_in[20]; const float* ob1 = (const float*)d_in[21];
  const float* oW2 = (const float*)d_in[22]; const float* ob2 = (const float*)d_in[23];

  float* W      = (float*)d_ws;
  float* h      = W;                                   // 1,048,576 f
  float* A1t    = W + 1048576;                         // 1,048,576 f
  unsigned short* A2bf   = (unsigned short*)(W + 2097152); // 1,048,576 bf16
  unsigned short* wfragE = (unsigned short*)(W + 2621440); // 16,384 bf16
  float* P      = W + 2629632;                         // 2560*1024 f
  float* g      = W + 5251072;                         // 1024 f
  int*   cntI   = (int*)(W + 5252096);                 // 1024
  int*   off    = cntI + 1024;                         // 1025
  int*   ioff   = off + 1025;                          // 1025
  int*   fill   = ioff + 1025;                         // 1024
  int*   items  = fill + 1024;                         // 2560
  int*   nitems = items + 2560;                        // 1
  int*   ecol   = nitems + 1;                          // 32768
  float* An1    = W + 5291776;                         // 65,536 f
  float* An2    = An1 + 65536;                         // 65,536 f
  float* Ag1    = An2 + 65536;                         // 1,024 f
  float* Ag2    = Ag1 + 1024;                          // 1,024 f

  hipMemsetAsync(cntI, 0, 1024*sizeof(int), stream);
  k_count <<<128, 256, 0, stream>>>(ei, cntI);
  k_scan  <<<1,  1024, 0, stream>>>(cntI, off, ioff, fill, items, nitems);
  k_bucket<<<128, 256, 0, stream>>>(ei, off, fill, ecol, eW2, wfragE, z, Wg, bg, g);
  k_preA  <<<65,  256, 0, stream>>>(nf, Wn, bn, g, eW1, eb1, An1, An2, Ag1, Ag2);
  k_pre1  <<<1024,256, 0, stream>>>(nf, Wn, bn, g, An1, An2, Ag1, Ag2, h, A1t, A2bf);

  for (int l = 0; l < 4; l++){
    k_edge<<<640, 256, 0, stream>>>(A1t, A2bf, wfragE, eb2, l, off, ecol,
                                    items, nitems, P);
    if (l < 3)
      k_post<false><<<256, 256, 0, stream>>>(l, h, P, ioff, nW1, nb1, nW2, nb2,
            lng, lnb, eW1, eb1, A1t, A2bf, oW1, ob1, oW2, ob2, (float*)d_out);
    else
      k_post<true> <<<256, 256, 0, stream>>>(l, h, P, ioff, nW1, nb1, nW2, nb2,
            lng, lnb, eW1, eb1, A1t, A2bf, oW1, ob1, oW2, ob2, (float*)d_out);
  }
}